// Round 8
// baseline (742.555 us; speedup 1.0000x reference)
//
#include <hip/hip_runtime.h>

#define CCH 96      // channels
#define C4  24
#define KK  27      // neighbors
#define NPB 64      // nodes per conv block
#define TPB 192     // threads per conv block
#define BN_EPS 1e-5f
#define QROW 96     // packed int8 row bytes (scale in separate array)

// conv geometry: 12 lanes x 8ch per node-row, 16 groups/block
#define LPG 12
#define GROUPS16 (TPB/LPG)        // 16
#define NPT16 (NPB/GROUPS16)      // 4
// fp32 fallback geometry
#define GROUPS8 8
#define NPT8 (NPB/GROUPS8)

typedef float floatx4 __attribute__((ext_vector_type(4)));
typedef unsigned short ushortx8 __attribute__((ext_vector_type(8)));
typedef signed char scharx8 __attribute__((ext_vector_type(8)));

__device__ __forceinline__ unsigned short f2bf_rne(float x){
    unsigned int u = __builtin_bit_cast(unsigned int, x);
    u += 0x7fffu + ((u >> 16) & 1u);
    return (unsigned short)(u >> 16);
}
__device__ __forceinline__ float bf2f(unsigned short h){
    unsigned int u = ((unsigned int)h) << 16;
    return __builtin_bit_cast(float, u);
}

// ---------------- fp32 -> int8 (96B packed rows) + separate scale array ----------------
// 64 rows/block, 256 threads = 64 rows x 4 lanes of 24 channels.
__global__ __launch_bounds__(256) void quant_kernel(
    const float* __restrict__ in, unsigned char* __restrict__ outq,
    float* __restrict__ scl, int N)
{
    __shared__ float buf[64*CCH];          // 24576 B
    __shared__ float pmax[64][4];
    __shared__ float pscl[64], pinv[64];
    __shared__ __align__(16) unsigned char qbuf[64*QROW];  // 6144 B

    const int tid = threadIdx.x;
    const long long base = (long long)blockIdx.x * 64;

    // stage 64 rows coalesced (1536 float4)
    floatx4* buf4 = (floatx4*)buf;
    const floatx4* in4 = (const floatx4*)in;
    for (int i = tid; i < 64*C4; i += 256) {
        const long long row = base + i / C4;
        buf4[i] = (row < N) ? in4[base*C4 + i] : (floatx4)0.f;
    }
    __syncthreads();

    const int r = tid >> 2;          // 0..63
    const int j = tid & 3;           // 0..3
    float m = 0.f;
    for (int c = j*24; c < j*24 + 24; ++c) m = fmaxf(m, fabsf(buf[r*CCH + c]));
    pmax[r][j] = m;
    __syncthreads();
    if (j == 0) {
        float mm = fmaxf(fmaxf(pmax[r][0], pmax[r][1]), fmaxf(pmax[r][2], pmax[r][3]));
        pscl[r] = mm * (1.f/127.f);
        pinv[r] = (mm > 0.f) ? (127.f / mm) : 0.f;
    }
    __syncthreads();
    const float inv = pinv[r];
    for (int c = j*24; c < j*24 + 24; ++c) {
        float q = rintf(buf[r*CCH + c] * inv);
        qbuf[r*QROW + c] = (unsigned char)(signed char)(int)q;
    }
    __syncthreads();

    // coalesced writeout: 64 rows * 96B = 384 x 16B
    uint4* out16 = (uint4*)outq;
    const uint4* q16 = (const uint4*)qbuf;
    for (int i = tid; i < 384; i += 256) {
        const long long row = base + i / 6;
        if (row < N) out16[base*6 + i] = q16[i];
    }
    // scales
    if (tid < 64 && base + tid < N) scl[base + tid] = pscl[tid];
}

// ---------------- int8 conv + per-block BN partials (bf16 out) ----------------
__global__ __launch_bounds__(TPB) void octconv_q8_kernel(
    const unsigned char* __restrict__ qdat,
    const float* __restrict__ scl,
    const int*   __restrict__ neigh32,
    const float* __restrict__ weight,
    unsigned short* __restrict__ outb,
    float*       __restrict__ partial,   // [gridDim.x][192]: 96 sum | 96 sumsq
    int N)
{
    __shared__ float w_lds[KK*CCH];                  // 10368 B
    __shared__ __align__(16) char u_lds[NPB*KK*4];   // 6912 B (nb, then red 6144 B)
    __shared__ int   flag_is64;
    int*   nb_lds = (int*)u_lds;
    float* red    = (float*)u_lds;

    const int tid  = threadIdx.x;
    const int l12  = tid % LPG;
    const int g    = tid / LPG;
    const int base = blockIdx.x * NPB;
    const long long totalK = (long long)N * KK;

    if (tid < 64) {
        int hi = neigh32[2*tid + 1];
        unsigned long long b = __ballot(hi != 0);
        if (tid == 0) flag_is64 = (b == 0ull) ? 1 : 0;
    }
    for (int i = tid; i < KK*CCH; i += TPB) w_lds[i] = weight[i];
    __syncthreads();

    const bool is64 = (flag_is64 != 0);
    const long long* neigh64 = (const long long*)neigh32;

    for (int i = tid; i < NPB*KK; i += TPB) {
        long long gi = (long long)base * KK + i;
        int v = -1;
        if (gi < totalK) {
            if (is64) { long long vv = __builtin_nontemporal_load(neigh64 + gi); v = (vv < 0) ? -1 : (int)vv; }
            else      { v = __builtin_nontemporal_load(neigh32 + gi); }
        }
        nb_lds[i] = v;
    }
    __syncthreads();

    floatx4 sA = (floatx4)0.f, sB = (floatx4)0.f;
    floatx4 qA = (floatx4)0.f, qB = (floatx4)0.f;
    const int ch0 = l12 * 8;

    for (int i = 0; i < NPT16; ++i) {
        const int local = g * NPT16 + i;
        const int n = base + local;
        if (n < N) {
            floatx4 accA = (floatx4)0.f, accB = (floatx4)0.f;
            #pragma unroll
            for (int k = 0; k < KK; ++k) {
                const int idx = nb_lds[local*KK + k];
                if (idx >= 0) {
                    const scharx8 dq = *(const scharx8*)(qdat + (long long)idx*QROW + ch0);
                    const float   s  = scl[idx];
                    const floatx4 wA = *(const floatx4*)(&w_lds[k*CCH + ch0]);
                    const floatx4 wB = *(const floatx4*)(&w_lds[k*CCH + ch0 + 4]);
                    floatx4 fA, fB;
                    fA.x=(float)dq[0]; fA.y=(float)dq[1]; fA.z=(float)dq[2]; fA.w=(float)dq[3];
                    fB.x=(float)dq[4]; fB.y=(float)dq[5]; fB.z=(float)dq[6]; fB.w=(float)dq[7];
                    accA += fA * (wA * s);
                    accB += fB * (wB * s);
                }
            }
            ushortx8 o;
            o[0]=f2bf_rne(accA.x); o[1]=f2bf_rne(accA.y); o[2]=f2bf_rne(accA.z); o[3]=f2bf_rne(accA.w);
            o[4]=f2bf_rne(accB.x); o[5]=f2bf_rne(accB.y); o[6]=f2bf_rne(accB.z); o[7]=f2bf_rne(accB.w);
            __builtin_nontemporal_store(o, (ushortx8*)(outb + (long long)n*CCH + ch0));
            sA += accA; sB += accB;
            qA += accA*accA; qB += accB*accB;
        }
    }

    __syncthreads();
    *(floatx4*)(&red[g*CCH + ch0])     = sA;
    *(floatx4*)(&red[g*CCH + ch0 + 4]) = sB;
    __syncthreads();
    if (tid < CCH) {
        float t = 0.f;
        #pragma unroll
        for (int gg = 0; gg < GROUPS16; ++gg) t += red[gg*CCH + tid];
        partial[blockIdx.x*2*CCH + tid] = t;
    }
    __syncthreads();
    *(floatx4*)(&red[g*CCH + ch0])     = qA;
    *(floatx4*)(&red[g*CCH + ch0 + 4]) = qB;
    __syncthreads();
    if (tid < CCH) {
        float t = 0.f;
        #pragma unroll
        for (int gg = 0; gg < GROUPS16; ++gg) t += red[gg*CCH + tid];
        partial[blockIdx.x*2*CCH + CCH + tid] = t;
    }
}

// ---------------- bf16 fallback: fp32->bf16 copy ----------------
__global__ __launch_bounds__(256) void cvt_kernel(
    const float* __restrict__ in, ushortx8* __restrict__ outp, long long total8)
{
    long long i = (long long)blockIdx.x * 256 + threadIdx.x;
    const long long stride = (long long)gridDim.x * 256;
    const floatx4* in4 = (const floatx4*)in;
    for (; i < total8; i += stride) {
        floatx4 a = in4[2*i], b = in4[2*i+1];
        ushortx8 o;
        o[0]=f2bf_rne(a.x); o[1]=f2bf_rne(a.y); o[2]=f2bf_rne(a.z); o[3]=f2bf_rne(a.w);
        o[4]=f2bf_rne(b.x); o[5]=f2bf_rne(b.y); o[6]=f2bf_rne(b.z); o[7]=f2bf_rne(b.w);
        outp[i] = o;
    }
}

// ---------------- bf16 fallback conv (proven R6 path, bf16 out) ----------------
__global__ __launch_bounds__(TPB) void octconv_bf16_kernel(
    const unsigned short* __restrict__ bdat,
    const int*   __restrict__ neigh32,
    const float* __restrict__ weight,
    unsigned short* __restrict__ outb,
    float*       __restrict__ partial,
    int N)
{
    __shared__ float w_lds[KK*CCH];
    __shared__ __align__(16) char u_lds[NPB*KK*4];
    __shared__ int   flag_is64;
    int*   nb_lds = (int*)u_lds;
    float* red    = (float*)u_lds;

    const int tid  = threadIdx.x;
    const int l12  = tid % LPG;
    const int g    = tid / LPG;
    const int base = blockIdx.x * NPB;
    const long long totalK = (long long)N * KK;

    if (tid < 64) {
        int hi = neigh32[2*tid + 1];
        unsigned long long b = __ballot(hi != 0);
        if (tid == 0) flag_is64 = (b == 0ull) ? 1 : 0;
    }
    for (int i = tid; i < KK*CCH; i += TPB) w_lds[i] = weight[i];
    __syncthreads();

    const bool is64 = (flag_is64 != 0);
    const long long* neigh64 = (const long long*)neigh32;

    for (int i = tid; i < NPB*KK; i += TPB) {
        long long gi = (long long)base * KK + i;
        int v = -1;
        if (gi < totalK) {
            if (is64) { long long vv = __builtin_nontemporal_load(neigh64 + gi); v = (vv < 0) ? -1 : (int)vv; }
            else      { v = __builtin_nontemporal_load(neigh32 + gi); }
        }
        nb_lds[i] = v;
    }
    __syncthreads();

    floatx4 sA = (floatx4)0.f, sB = (floatx4)0.f;
    floatx4 qA = (floatx4)0.f, qB = (floatx4)0.f;
    const int ch0 = l12 * 8;

    for (int i = 0; i < NPT16; ++i) {
        const int local = g * NPT16 + i;
        const int n = base + local;
        if (n < N) {
            floatx4 accA = (floatx4)0.f, accB = (floatx4)0.f;
            #pragma unroll
            for (int k = 0; k < KK; ++k) {
                const int idx = nb_lds[local*KK + k];
                if (idx >= 0) {
                    const ushortx8 d = *(const ushortx8*)(bdat + (long long)idx*CCH + ch0);
                    const floatx4 wA = *(const floatx4*)(&w_lds[k*CCH + ch0]);
                    const floatx4 wB = *(const floatx4*)(&w_lds[k*CCH + ch0 + 4]);
                    floatx4 fA, fB;
                    fA.x=bf2f(d[0]); fA.y=bf2f(d[1]); fA.z=bf2f(d[2]); fA.w=bf2f(d[3]);
                    fB.x=bf2f(d[4]); fB.y=bf2f(d[5]); fB.z=bf2f(d[6]); fB.w=bf2f(d[7]);
                    accA += fA * wA;
                    accB += fB * wB;
                }
            }
            ushortx8 o;
            o[0]=f2bf_rne(accA.x); o[1]=f2bf_rne(accA.y); o[2]=f2bf_rne(accA.z); o[3]=f2bf_rne(accA.w);
            o[4]=f2bf_rne(accB.x); o[5]=f2bf_rne(accB.y); o[6]=f2bf_rne(accB.z); o[7]=f2bf_rne(accB.w);
            __builtin_nontemporal_store(o, (ushortx8*)(outb + (long long)n*CCH + ch0));
            sA += accA; sB += accB;
            qA += accA*accA; qB += accB*accB;
        }
    }

    __syncthreads();
    *(floatx4*)(&red[g*CCH + ch0])     = sA;
    *(floatx4*)(&red[g*CCH + ch0 + 4]) = sB;
    __syncthreads();
    if (tid < CCH) {
        float t = 0.f;
        #pragma unroll
        for (int gg = 0; gg < GROUPS16; ++gg) t += red[gg*CCH + tid];
        partial[blockIdx.x*2*CCH + tid] = t;
    }
    __syncthreads();
    *(floatx4*)(&red[g*CCH + ch0])     = qA;
    *(floatx4*)(&red[g*CCH + ch0 + 4]) = qB;
    __syncthreads();
    if (tid < CCH) {
        float t = 0.f;
        #pragma unroll
        for (int gg = 0; gg < GROUPS16; ++gg) t += red[gg*CCH + tid];
        partial[blockIdx.x*2*CCH + CCH + tid] = t;
    }
}

// ---------------- fp32 full-fallback conv ----------------
__global__ __launch_bounds__(TPB) void octconv_f32_kernel(
    const float* __restrict__ data,
    const int*   __restrict__ neigh32,
    const float* __restrict__ weight,
    float*       __restrict__ out,
    float*       __restrict__ partial,
    int N)
{
    __shared__ float w_lds[KK*CCH];
    __shared__ __align__(16) char u_lds[NPB*KK*4];
    __shared__ int   flag_is64;
    int*   nb_lds = (int*)u_lds;
    float* red    = (float*)u_lds;

    const int tid = threadIdx.x;
    const int c4  = tid % C4;
    const int g   = tid / C4;
    const int base = blockIdx.x * NPB;
    const long long totalK = (long long)N * KK;

    if (tid < 64) {
        int hi = neigh32[2*tid + 1];
        unsigned long long b = __ballot(hi != 0);
        if (tid == 0) flag_is64 = (b == 0ull) ? 1 : 0;
    }
    for (int i = tid; i < KK*CCH; i += TPB) w_lds[i] = weight[i];
    __syncthreads();

    const bool is64 = (flag_is64 != 0);
    const long long* neigh64 = (const long long*)neigh32;

    for (int i = tid; i < NPB*KK; i += TPB) {
        long long gi = (long long)base * KK + i;
        int v = -1;
        if (gi < totalK) {
            if (is64) { long long vv = __builtin_nontemporal_load(neigh64 + gi); v = (vv < 0) ? -1 : (int)vv; }
            else      { v = __builtin_nontemporal_load(neigh32 + gi); }
        }
        nb_lds[i] = v;
    }
    __syncthreads();

    const floatx4* w4 = (const floatx4*)w_lds;
    floatx4 s = (floatx4)0.f, q = (floatx4)0.f;

    for (int i = 0; i < NPT8; ++i) {
        const int local = g * NPT8 + i;
        const int n = base + local;
        if (n < N) {
            floatx4 acc = (floatx4)0.f;
            #pragma unroll
            for (int k = 0; k < KK; ++k) {
                const int idx = nb_lds[local*KK + k];
                if (idx >= 0) {
                    const floatx4 d = *(const floatx4*)(data + (long long)idx*CCH + c4*4);
                    acc += d * w4[k*C4 + c4];
                }
            }
            __builtin_nontemporal_store(acc, (floatx4*)(out + (long long)n*CCH + c4*4));
            s += acc; q += acc*acc;
        }
    }

    __syncthreads();
    *(floatx4*)(&red[g*CCH + c4*4]) = s;
    __syncthreads();
    if (g == 0) {
        floatx4 ts = (floatx4)0.f;
        #pragma unroll
        for (int gg = 0; gg < GROUPS8; ++gg) ts += *(floatx4*)(&red[gg*CCH + c4*4]);
        *(floatx4*)(partial + blockIdx.x*2*CCH + c4*4) = ts;
    }
    __syncthreads();
    *(floatx4*)(&red[g*CCH + c4*4]) = q;
    __syncthreads();
    if (g == 0) {
        floatx4 tq = (floatx4)0.f;
        #pragma unroll
        for (int gg = 0; gg < GROUPS8; ++gg) tq += *(floatx4*)(&red[gg*CCH + c4*4]);
        *(floatx4*)(partial + blockIdx.x*2*CCH + CCH + c4*4) = tq;
    }
}

// ---------------- stage-1 reduce ----------------
__global__ __launch_bounds__(192) void reduce1_kernel(
    const float* __restrict__ partial, float* __restrict__ out2, int nblocks)
{
    const int col = threadIdx.x;
    float s = 0.f;
    for (int r = blockIdx.x; r < nblocks; r += gridDim.x)
        s += partial[r*192 + col];
    out2[blockIdx.x*192 + col] = s;
}

// ---------------- stage-2 reduce + scale/shift ----------------
__global__ __launch_bounds__(192) void reduce2_kernel(
    const float* __restrict__ in2, const float* __restrict__ gamma,
    const float* __restrict__ beta, float* __restrict__ scaleshift, int N)
{
    __shared__ float arr[192];
    const int col = threadIdx.x;
    float s = 0.f;
    for (int r = 0; r < 96; ++r) s += in2[r*192 + col];
    arr[col] = s;
    __syncthreads();
    if (col < CCH) {
        float invN = 1.f / (float)N;
        float mean = arr[col] * invN;
        float var  = arr[CCH + col] * invN - mean*mean;
        float sc   = gamma[col] * rsqrtf(var + BN_EPS);
        scaleshift[col]       = sc;
        scaleshift[CCH + col] = beta[col] - mean*sc;
    }
}

// ---------------- apply BN: bf16 in (ws) -> fp32 out ----------------
__global__ __launch_bounds__(256) void bn_apply_bf16_kernel(
    const unsigned short* __restrict__ outb,
    float* __restrict__ out,
    const float* __restrict__ scaleshift, long long total12)
{
    __shared__ float sc[CCH], sh[CCH];
    const int tid = threadIdx.x;
    if (tid < CCH) { sc[tid] = scaleshift[tid]; sh[tid] = scaleshift[CCH + tid]; }
    __syncthreads();
    const long long stride = (long long)gridDim.x * blockDim.x;
    long long i = (long long)blockIdx.x * blockDim.x + tid;
    const int ch0 = (int)(i % LPG) * 8;
    const floatx4 a0 = *(const floatx4*)(&sc[ch0]);
    const floatx4 a1 = *(const floatx4*)(&sc[ch0+4]);
    const floatx4 b0 = *(const floatx4*)(&sh[ch0]);
    const floatx4 b1 = *(const floatx4*)(&sh[ch0+4]);
    for (; i < total12; i += stride) {
        const long long n = i / LPG;
        const ushortx8 d = __builtin_nontemporal_load((const ushortx8*)(outb + n*CCH + ch0));
        floatx4 vA, vB;
        vA.x=bf2f(d[0]); vA.y=bf2f(d[1]); vA.z=bf2f(d[2]); vA.w=bf2f(d[3]);
        vB.x=bf2f(d[4]); vB.y=bf2f(d[5]); vB.z=bf2f(d[6]); vB.w=bf2f(d[7]);
        vA = vA*a0 + b0;
        vB = vB*a1 + b1;
        __builtin_nontemporal_store(vA, (floatx4*)(out + n*CCH + ch0));
        __builtin_nontemporal_store(vB, (floatx4*)(out + n*CCH + ch0 + 4));
    }
}

// ---------------- apply BN in place (fp32 fallback) ----------------
__global__ __launch_bounds__(256) void bn_apply_kernel(
    float* __restrict__ out, const float* __restrict__ scaleshift, long long total4)
{
    __shared__ float4 sc[C4], sh[C4];
    const int tid = threadIdx.x;
    if (tid < C4) {
        sc[tid] = ((const float4*)scaleshift)[tid];
        sh[tid] = ((const float4*)(scaleshift + CCH))[tid];
    }
    __syncthreads();
    const long long stride = (long long)gridDim.x * blockDim.x;
    long long i = (long long)blockIdx.x * blockDim.x + tid;
    const int c4 = (int)(i % C4);
    const float4 a = sc[c4], b = sh[c4];
    float4* o4 = (float4*)out;
    for (; i < total4; i += stride) {
        float4 v = o4[i];
        v.x = v.x*a.x + b.x; v.y = v.y*a.y + b.y;
        v.z = v.z*a.z + b.z; v.w = v.w*a.w + b.w;
        o4[i] = v;
    }
}

extern "C" void kernel_launch(void* const* d_in, const int* in_sizes, int n_in,
                              void* d_out, int out_size, void* d_ws, size_t ws_size,
                              hipStream_t stream) {
    const float* data   = (const float*)d_in[0];
    const int*   neigh  = (const int*)d_in[1];
    const float* weight = (const float*)d_in[2];
    const float* gamma  = (const float*)d_in[3];
    const float* beta   = (const float*)d_in[4];
    float* out = (float*)d_out;

    const int N = in_sizes[0] / CCH;
    const int nblocks = (N + NPB - 1) / NPB;

    const size_t q_bytes   = ((size_t)N * QROW + 255) & ~(size_t)255;
    const size_t s_bytes   = ((size_t)N * 4 + 255) & ~(size_t)255;
    const size_t bf_bytes  = ((size_t)N * CCH * 2 + 255) & ~(size_t)255;
    const size_t red_bytes = ((size_t)nblocks * 192 + 96*192 + 192) * 4;

    if (ws_size >= q_bytes + s_bytes + bf_bytes + red_bytes) {
        // int8 96B-row gather + L2-resident scale array + bf16 out staging
        unsigned char* qdat  = (unsigned char*)d_ws;
        float* scl           = (float*)((char*)d_ws + q_bytes);
        unsigned short* outb = (unsigned short*)((char*)d_ws + q_bytes + s_bytes);
        float* wsA = (float*)((char*)d_ws + q_bytes + s_bytes + bf_bytes);
        float* wsB = wsA + (size_t)nblocks * 192;
        float* wsC = wsB + 96 * 192;
        quant_kernel<<<(N + 63)/64, 256, 0, stream>>>(data, qdat, scl, N);
        octconv_q8_kernel<<<nblocks, TPB, 0, stream>>>(qdat, scl, neigh, weight, outb, wsA, N);
        reduce1_kernel<<<96, 192, 0, stream>>>(wsA, wsB, nblocks);
        reduce2_kernel<<<1, 192, 0, stream>>>(wsB, gamma, beta, wsC, N);
        bn_apply_bf16_kernel<<<2040, 256, 0, stream>>>(outb, out, wsC, (long long)N * LPG);
    } else if (ws_size >= 2*bf_bytes + red_bytes) {
        // proven R6 path
        unsigned short* bdat = (unsigned short*)d_ws;
        unsigned short* outb = (unsigned short*)((char*)d_ws + bf_bytes);
        float* wsA = (float*)((char*)d_ws + 2*bf_bytes);
        float* wsB = wsA + (size_t)nblocks * 192;
        float* wsC = wsB + 96 * 192;
        cvt_kernel<<<2048, 256, 0, stream>>>(data, (ushortx8*)bdat, (long long)N*CCH/8);
        octconv_bf16_kernel<<<nblocks, TPB, 0, stream>>>(bdat, neigh, weight, outb, wsA, N);
        reduce1_kernel<<<96, 192, 0, stream>>>(wsA, wsB, nblocks);
        reduce2_kernel<<<1, 192, 0, stream>>>(wsB, gamma, beta, wsC, N);
        bn_apply_bf16_kernel<<<2040, 256, 0, stream>>>(outb, out, wsC, (long long)N * LPG);
    } else {
        float* wsA = (float*)d_ws;
        float* wsB = wsA + (size_t)nblocks * 192;
        float* wsC = wsB + 96 * 192;
        octconv_f32_kernel<<<nblocks, TPB, 0, stream>>>(data, neigh, weight, out, wsA, N);
        reduce1_kernel<<<96, 192, 0, stream>>>(wsA, wsB, nblocks);
        reduce2_kernel<<<1, 192, 0, stream>>>(wsB, gamma, beta, wsC, N);
        bn_apply_kernel<<<2040, 256, 0, stream>>>(out, wsC, (long long)N * C4);
    }
}

// Round 9
// 522.350 us; speedup vs baseline: 1.4216x; 1.4216x over previous
//
#include <hip/hip_runtime.h>

#define CCH 96      // channels
#define C4  24
#define KK  27      // neighbors
#define NPB 64      // nodes per conv block
#define TPB 192     // threads per conv block
#define BN_EPS 1e-5f
#define QROW 128    // padded int8 row bytes: 96 int8 + 4B scale + pad (2 aligned lines)

// conv geometry: 12 lanes x 8ch per node-row, 16 groups/block
#define LPG 12
#define GROUPS16 (TPB/LPG)        // 16
#define NPT16 (NPB/GROUPS16)      // 4
// fp32 fallback geometry
#define GROUPS8 8
#define NPT8 (NPB/GROUPS8)

typedef float floatx4 __attribute__((ext_vector_type(4)));
typedef unsigned short ushortx8 __attribute__((ext_vector_type(8)));
typedef signed char scharx8 __attribute__((ext_vector_type(8)));

__device__ __forceinline__ unsigned short f2bf_rne(float x){
    unsigned int u = __builtin_bit_cast(unsigned int, x);
    u += 0x7fffu + ((u >> 16) & 1u);
    return (unsigned short)(u >> 16);
}
__device__ __forceinline__ float bf2f(unsigned short h){
    unsigned int u = ((unsigned int)h) << 16;
    return __builtin_bit_cast(float, u);
}

// ---------------- fp32 -> int8(per-row scale) quantize ----------------
// 64 rows/block, 256 threads = 64 rows x 4 lanes of 24 channels.
__global__ __launch_bounds__(256) void quant_kernel(
    const float* __restrict__ in, unsigned char* __restrict__ outq, int N)
{
    __shared__ float buf[64*CCH];          // 24576 B
    __shared__ float pmax[64][4];
    __shared__ float pscl[64], pinv[64];
    __shared__ __align__(16) unsigned char qbuf[64*QROW];  // 8192 B

    const int tid = threadIdx.x;
    const long long base = (long long)blockIdx.x * 64;

    // stage 64 rows coalesced (1536 float4)
    floatx4* buf4 = (floatx4*)buf;
    const floatx4* in4 = (const floatx4*)in;
    for (int i = tid; i < 64*C4; i += 256) {
        const long long row = base + i / C4;
        buf4[i] = (row < N) ? in4[base*C4 + i] : (floatx4)0.f;
    }
    __syncthreads();

    const int r = tid >> 2;          // 0..63
    const int j = tid & 3;           // 0..3
    float m = 0.f;
    for (int c = j*24; c < j*24 + 24; ++c) m = fmaxf(m, fabsf(buf[r*CCH + c]));
    pmax[r][j] = m;
    __syncthreads();
    if (j == 0) {
        float mm = fmaxf(fmaxf(pmax[r][0], pmax[r][1]), fmaxf(pmax[r][2], pmax[r][3]));
        pscl[r] = mm * (1.f/127.f);
        pinv[r] = (mm > 0.f) ? (127.f / mm) : 0.f;
    }
    __syncthreads();
    const float inv = pinv[r];
    for (int c = j*24; c < j*24 + 24; ++c) {
        float q = rintf(buf[r*CCH + c] * inv);
        qbuf[r*QROW + c] = (unsigned char)(signed char)(int)q;
    }
    if (j == 0) {
        *(float*)(qbuf + r*QROW + 96) = pscl[r];
        for (int b = 100; b < QROW; b += 4) *(int*)(qbuf + r*QROW + b) = 0;
    }
    __syncthreads();

    // coalesced writeout: 64*128B = 512 x 16B
    uint4* out16 = (uint4*)outq;
    const uint4* q16 = (const uint4*)qbuf;
    for (int i = tid; i < 512; i += 256) {
        const long long row = base + (i >> 3);
        if (row < N) out16[base*8 + i] = q16[i];
    }
}

// ---------------- int8 conv + per-block BN partials (bf16 out) ----------------
__global__ __launch_bounds__(TPB) void octconv_q8_kernel(
    const unsigned char* __restrict__ qdat,
    const int*   __restrict__ neigh32,
    const float* __restrict__ weight,
    unsigned short* __restrict__ outb,
    float*       __restrict__ partial,   // [gridDim.x][192]: 96 sum | 96 sumsq
    int N)
{
    __shared__ float w_lds[KK*CCH];                  // 10368 B
    __shared__ __align__(16) char u_lds[NPB*KK*4];   // 6912 B (nb, then red 6144 B)
    __shared__ int   flag_is64;
    int*   nb_lds = (int*)u_lds;
    float* red    = (float*)u_lds;

    const int tid  = threadIdx.x;
    const int l12  = tid % LPG;
    const int g    = tid / LPG;
    const int base = blockIdx.x * NPB;
    const long long totalK = (long long)N * KK;

    if (tid < 64) {
        int hi = neigh32[2*tid + 1];
        unsigned long long b = __ballot(hi != 0);
        if (tid == 0) flag_is64 = (b == 0ull) ? 1 : 0;
    }
    for (int i = tid; i < KK*CCH; i += TPB) w_lds[i] = weight[i];
    __syncthreads();

    const bool is64 = (flag_is64 != 0);
    const long long* neigh64 = (const long long*)neigh32;

    for (int i = tid; i < NPB*KK; i += TPB) {
        long long gi = (long long)base * KK + i;
        int v = -1;
        if (gi < totalK) {
            if (is64) { long long vv = __builtin_nontemporal_load(neigh64 + gi); v = (vv < 0) ? -1 : (int)vv; }
            else      { v = __builtin_nontemporal_load(neigh32 + gi); }
        }
        nb_lds[i] = v;
    }
    __syncthreads();

    floatx4 sA = (floatx4)0.f, sB = (floatx4)0.f;
    floatx4 qA = (floatx4)0.f, qB = (floatx4)0.f;
    const int ch0 = l12 * 8;

    for (int i = 0; i < NPT16; ++i) {
        const int local = g * NPT16 + i;
        const int n = base + local;
        if (n < N) {
            floatx4 accA = (floatx4)0.f, accB = (floatx4)0.f;
            #pragma unroll
            for (int k = 0; k < KK; ++k) {
                const int idx = nb_lds[local*KK + k];
                if (idx >= 0) {
                    const unsigned char* rp = qdat + ((long long)idx << 7);
                    const scharx8 dq = *(const scharx8*)(rp + ch0);
                    const float   s  = *(const float*)(rp + 96);
                    const floatx4 wA = *(const floatx4*)(&w_lds[k*CCH + ch0]);
                    const floatx4 wB = *(const floatx4*)(&w_lds[k*CCH + ch0 + 4]);
                    floatx4 fA, fB;
                    fA.x=(float)dq[0]; fA.y=(float)dq[1]; fA.z=(float)dq[2]; fA.w=(float)dq[3];
                    fB.x=(float)dq[4]; fB.y=(float)dq[5]; fB.z=(float)dq[6]; fB.w=(float)dq[7];
                    accA += fA * (wA * s);
                    accB += fB * (wB * s);
                }
            }
            ushortx8 o;
            o[0]=f2bf_rne(accA.x); o[1]=f2bf_rne(accA.y); o[2]=f2bf_rne(accA.z); o[3]=f2bf_rne(accA.w);
            o[4]=f2bf_rne(accB.x); o[5]=f2bf_rne(accB.y); o[6]=f2bf_rne(accB.z); o[7]=f2bf_rne(accB.w);
            __builtin_nontemporal_store(o, (ushortx8*)(outb + (long long)n*CCH + ch0));
            sA += accA; sB += accB;
            qA += accA*accA; qB += accB*accB;
        }
    }

    __syncthreads();
    *(floatx4*)(&red[g*CCH + ch0])     = sA;
    *(floatx4*)(&red[g*CCH + ch0 + 4]) = sB;
    __syncthreads();
    if (tid < CCH) {
        float t = 0.f;
        #pragma unroll
        for (int gg = 0; gg < GROUPS16; ++gg) t += red[gg*CCH + tid];
        partial[blockIdx.x*2*CCH + tid] = t;
    }
    __syncthreads();
    *(floatx4*)(&red[g*CCH + ch0])     = qA;
    *(floatx4*)(&red[g*CCH + ch0 + 4]) = qB;
    __syncthreads();
    if (tid < CCH) {
        float t = 0.f;
        #pragma unroll
        for (int gg = 0; gg < GROUPS16; ++gg) t += red[gg*CCH + tid];
        partial[blockIdx.x*2*CCH + CCH + tid] = t;
    }
}

// ---------------- bf16 fallback: fp32->bf16 copy ----------------
__global__ __launch_bounds__(256) void cvt_kernel(
    const float* __restrict__ in, ushortx8* __restrict__ outp, long long total8)
{
    long long i = (long long)blockIdx.x * 256 + threadIdx.x;
    const long long stride = (long long)gridDim.x * 256;
    const floatx4* in4 = (const floatx4*)in;
    for (; i < total8; i += stride) {
        floatx4 a = in4[2*i], b = in4[2*i+1];
        ushortx8 o;
        o[0]=f2bf_rne(a.x); o[1]=f2bf_rne(a.y); o[2]=f2bf_rne(a.z); o[3]=f2bf_rne(a.w);
        o[4]=f2bf_rne(b.x); o[5]=f2bf_rne(b.y); o[6]=f2bf_rne(b.z); o[7]=f2bf_rne(b.w);
        outp[i] = o;
    }
}

// ---------------- bf16 fallback conv (R6 path, bf16 out) ----------------
__global__ __launch_bounds__(TPB) void octconv_bf16_kernel(
    const unsigned short* __restrict__ bdat,
    const int*   __restrict__ neigh32,
    const float* __restrict__ weight,
    unsigned short* __restrict__ outb,
    float*       __restrict__ partial,
    int N)
{
    __shared__ float w_lds[KK*CCH];
    __shared__ __align__(16) char u_lds[NPB*KK*4];
    __shared__ int   flag_is64;
    int*   nb_lds = (int*)u_lds;
    float* red    = (float*)u_lds;

    const int tid  = threadIdx.x;
    const int l12  = tid % LPG;
    const int g    = tid / LPG;
    const int base = blockIdx.x * NPB;
    const long long totalK = (long long)N * KK;

    if (tid < 64) {
        int hi = neigh32[2*tid + 1];
        unsigned long long b = __ballot(hi != 0);
        if (tid == 0) flag_is64 = (b == 0ull) ? 1 : 0;
    }
    for (int i = tid; i < KK*CCH; i += TPB) w_lds[i] = weight[i];
    __syncthreads();

    const bool is64 = (flag_is64 != 0);
    const long long* neigh64 = (const long long*)neigh32;

    for (int i = tid; i < NPB*KK; i += TPB) {
        long long gi = (long long)base * KK + i;
        int v = -1;
        if (gi < totalK) {
            if (is64) { long long vv = __builtin_nontemporal_load(neigh64 + gi); v = (vv < 0) ? -1 : (int)vv; }
            else      { v = __builtin_nontemporal_load(neigh32 + gi); }
        }
        nb_lds[i] = v;
    }
    __syncthreads();

    floatx4 sA = (floatx4)0.f, sB = (floatx4)0.f;
    floatx4 qA = (floatx4)0.f, qB = (floatx4)0.f;
    const int ch0 = l12 * 8;

    for (int i = 0; i < NPT16; ++i) {
        const int local = g * NPT16 + i;
        const int n = base + local;
        if (n < N) {
            floatx4 accA = (floatx4)0.f, accB = (floatx4)0.f;
            #pragma unroll
            for (int k = 0; k < KK; ++k) {
                const int idx = nb_lds[local*KK + k];
                if (idx >= 0) {
                    const ushortx8 d = *(const ushortx8*)(bdat + (long long)idx*CCH + ch0);
                    const floatx4 wA = *(const floatx4*)(&w_lds[k*CCH + ch0]);
                    const floatx4 wB = *(const floatx4*)(&w_lds[k*CCH + ch0 + 4]);
                    floatx4 fA, fB;
                    fA.x=bf2f(d[0]); fA.y=bf2f(d[1]); fA.z=bf2f(d[2]); fA.w=bf2f(d[3]);
                    fB.x=bf2f(d[4]); fB.y=bf2f(d[5]); fB.z=bf2f(d[6]); fB.w=bf2f(d[7]);
                    accA += fA * wA;
                    accB += fB * wB;
                }
            }
            ushortx8 o;
            o[0]=f2bf_rne(accA.x); o[1]=f2bf_rne(accA.y); o[2]=f2bf_rne(accA.z); o[3]=f2bf_rne(accA.w);
            o[4]=f2bf_rne(accB.x); o[5]=f2bf_rne(accB.y); o[6]=f2bf_rne(accB.z); o[7]=f2bf_rne(accB.w);
            __builtin_nontemporal_store(o, (ushortx8*)(outb + (long long)n*CCH + ch0));
            sA += accA; sB += accB;
            qA += accA*accA; qB += accB*accB;
        }
    }

    __syncthreads();
    *(floatx4*)(&red[g*CCH + ch0])     = sA;
    *(floatx4*)(&red[g*CCH + ch0 + 4]) = sB;
    __syncthreads();
    if (tid < CCH) {
        float t = 0.f;
        #pragma unroll
        for (int gg = 0; gg < GROUPS16; ++gg) t += red[gg*CCH + tid];
        partial[blockIdx.x*2*CCH + tid] = t;
    }
    __syncthreads();
    *(floatx4*)(&red[g*CCH + ch0])     = qA;
    *(floatx4*)(&red[g*CCH + ch0 + 4]) = qB;
    __syncthreads();
    if (tid < CCH) {
        float t = 0.f;
        #pragma unroll
        for (int gg = 0; gg < GROUPS16; ++gg) t += red[gg*CCH + tid];
        partial[blockIdx.x*2*CCH + CCH + tid] = t;
    }
}

// ---------------- fp32 full-fallback conv ----------------
__global__ __launch_bounds__(TPB) void octconv_f32_kernel(
    const float* __restrict__ data,
    const int*   __restrict__ neigh32,
    const float* __restrict__ weight,
    float*       __restrict__ out,
    float*       __restrict__ partial,
    int N)
{
    __shared__ float w_lds[KK*CCH];
    __shared__ __align__(16) char u_lds[NPB*KK*4];
    __shared__ int   flag_is64;
    int*   nb_lds = (int*)u_lds;
    float* red    = (float*)u_lds;

    const int tid = threadIdx.x;
    const int c4  = tid % C4;
    const int g   = tid / C4;
    const int base = blockIdx.x * NPB;
    const long long totalK = (long long)N * KK;

    if (tid < 64) {
        int hi = neigh32[2*tid + 1];
        unsigned long long b = __ballot(hi != 0);
        if (tid == 0) flag_is64 = (b == 0ull) ? 1 : 0;
    }
    for (int i = tid; i < KK*CCH; i += TPB) w_lds[i] = weight[i];
    __syncthreads();

    const bool is64 = (flag_is64 != 0);
    const long long* neigh64 = (const long long*)neigh32;

    for (int i = tid; i < NPB*KK; i += TPB) {
        long long gi = (long long)base * KK + i;
        int v = -1;
        if (gi < totalK) {
            if (is64) { long long vv = __builtin_nontemporal_load(neigh64 + gi); v = (vv < 0) ? -1 : (int)vv; }
            else      { v = __builtin_nontemporal_load(neigh32 + gi); }
        }
        nb_lds[i] = v;
    }
    __syncthreads();

    const floatx4* w4 = (const floatx4*)w_lds;
    floatx4 s = (floatx4)0.f, q = (floatx4)0.f;

    for (int i = 0; i < NPT8; ++i) {
        const int local = g * NPT8 + i;
        const int n = base + local;
        if (n < N) {
            floatx4 acc = (floatx4)0.f;
            #pragma unroll
            for (int k = 0; k < KK; ++k) {
                const int idx = nb_lds[local*KK + k];
                if (idx >= 0) {
                    const floatx4 d = *(const floatx4*)(data + (long long)idx*CCH + c4*4);
                    acc += d * w4[k*C4 + c4];
                }
            }
            __builtin_nontemporal_store(acc, (floatx4*)(out + (long long)n*CCH + c4*4));
            s += acc; q += acc*acc;
        }
    }

    __syncthreads();
    *(floatx4*)(&red[g*CCH + c4*4]) = s;
    __syncthreads();
    if (g == 0) {
        floatx4 ts = (floatx4)0.f;
        #pragma unroll
        for (int gg = 0; gg < GROUPS8; ++gg) ts += *(floatx4*)(&red[gg*CCH + c4*4]);
        *(floatx4*)(partial + blockIdx.x*2*CCH + c4*4) = ts;
    }
    __syncthreads();
    *(floatx4*)(&red[g*CCH + c4*4]) = q;
    __syncthreads();
    if (g == 0) {
        floatx4 tq = (floatx4)0.f;
        #pragma unroll
        for (int gg = 0; gg < GROUPS8; ++gg) tq += *(floatx4*)(&red[gg*CCH + c4*4]);
        *(floatx4*)(partial + blockIdx.x*2*CCH + CCH + c4*4) = tq;
    }
}

// ---------------- stage-1 reduce ----------------
__global__ __launch_bounds__(192) void reduce1_kernel(
    const float* __restrict__ partial, float* __restrict__ out2, int nblocks)
{
    const int col = threadIdx.x;
    float s = 0.f;
    for (int r = blockIdx.x; r < nblocks; r += gridDim.x)
        s += partial[r*192 + col];
    out2[blockIdx.x*192 + col] = s;
}

// ---------------- stage-2 reduce + scale/shift ----------------
__global__ __launch_bounds__(192) void reduce2_kernel(
    const float* __restrict__ in2, const float* __restrict__ gamma,
    const float* __restrict__ beta, float* __restrict__ scaleshift, int N)
{
    __shared__ float arr[192];
    const int col = threadIdx.x;
    float s = 0.f;
    for (int r = 0; r < 96; ++r) s += in2[r*192 + col];
    arr[col] = s;
    __syncthreads();
    if (col < CCH) {
        float invN = 1.f / (float)N;
        float mean = arr[col] * invN;
        float var  = arr[CCH + col] * invN - mean*mean;
        float sc   = gamma[col] * rsqrtf(var + BN_EPS);
        scaleshift[col]       = sc;
        scaleshift[CCH + col] = beta[col] - mean*sc;
    }
}

// ---------------- apply BN: bf16 in (ws) -> fp32 out ----------------
__global__ __launch_bounds__(256) void bn_apply_bf16_kernel(
    const unsigned short* __restrict__ outb,
    float* __restrict__ out,
    const float* __restrict__ scaleshift, long long total12)
{
    __shared__ float sc[CCH], sh[CCH];
    const int tid = threadIdx.x;
    if (tid < CCH) { sc[tid] = scaleshift[tid]; sh[tid] = scaleshift[CCH + tid]; }
    __syncthreads();
    const long long stride = (long long)gridDim.x * blockDim.x;
    long long i = (long long)blockIdx.x * blockDim.x + tid;
    const int ch0 = (int)(i % LPG) * 8;
    const floatx4 a0 = *(const floatx4*)(&sc[ch0]);
    const floatx4 a1 = *(const floatx4*)(&sc[ch0+4]);
    const floatx4 b0 = *(const floatx4*)(&sh[ch0]);
    const floatx4 b1 = *(const floatx4*)(&sh[ch0+4]);
    for (; i < total12; i += stride) {
        const long long n = i / LPG;
        const ushortx8 d = __builtin_nontemporal_load((const ushortx8*)(outb + n*CCH + ch0));
        floatx4 vA, vB;
        vA.x=bf2f(d[0]); vA.y=bf2f(d[1]); vA.z=bf2f(d[2]); vA.w=bf2f(d[3]);
        vB.x=bf2f(d[4]); vB.y=bf2f(d[5]); vB.z=bf2f(d[6]); vB.w=bf2f(d[7]);
        vA = vA*a0 + b0;
        vB = vB*a1 + b1;
        __builtin_nontemporal_store(vA, (floatx4*)(out + n*CCH + ch0));
        __builtin_nontemporal_store(vB, (floatx4*)(out + n*CCH + ch0 + 4));
    }
}

// ---------------- apply BN in place (fp32 fallback) ----------------
__global__ __launch_bounds__(256) void bn_apply_kernel(
    float* __restrict__ out, const float* __restrict__ scaleshift, long long total4)
{
    __shared__ float4 sc[C4], sh[C4];
    const int tid = threadIdx.x;
    if (tid < C4) {
        sc[tid] = ((const float4*)scaleshift)[tid];
        sh[tid] = ((const float4*)(scaleshift + CCH))[tid];
    }
    __syncthreads();
    const long long stride = (long long)gridDim.x * blockDim.x;
    long long i = (long long)blockIdx.x * blockDim.x + tid;
    const int c4 = (int)(i % C4);
    const float4 a = sc[c4], b = sh[c4];
    float4* o4 = (float4*)out;
    for (; i < total4; i += stride) {
        float4 v = o4[i];
        v.x = v.x*a.x + b.x; v.y = v.y*a.y + b.y;
        v.z = v.z*a.z + b.z; v.w = v.w*a.w + b.w;
        o4[i] = v;
    }
}

extern "C" void kernel_launch(void* const* d_in, const int* in_sizes, int n_in,
                              void* d_out, int out_size, void* d_ws, size_t ws_size,
                              hipStream_t stream) {
    const float* data   = (const float*)d_in[0];
    const int*   neigh  = (const int*)d_in[1];
    const float* weight = (const float*)d_in[2];
    const float* gamma  = (const float*)d_in[3];
    const float* beta   = (const float*)d_in[4];
    float* out = (float*)d_out;

    const int N = in_sizes[0] / CCH;
    const int nblocks = (N + NPB - 1) / NPB;

    const size_t q_bytes   = ((size_t)N * QROW + 255) & ~(size_t)255;
    const size_t bf_bytes  = ((size_t)N * CCH * 2 + 255) & ~(size_t)255;
    const size_t red_bytes = ((size_t)nblocks * 192 + 96*192 + 192) * 4;

    if (ws_size >= q_bytes + bf_bytes + red_bytes) {
        // int8 gather + bf16 out staging
        unsigned char* qdat  = (unsigned char*)d_ws;
        unsigned short* outb = (unsigned short*)((char*)d_ws + q_bytes);
        float* wsA = (float*)((char*)d_ws + q_bytes + bf_bytes);
        float* wsB = wsA + (size_t)nblocks * 192;
        float* wsC = wsB + 96 * 192;
        quant_kernel<<<(N + 63)/64, 256, 0, stream>>>(data, qdat, N);
        octconv_q8_kernel<<<nblocks, TPB, 0, stream>>>(qdat, neigh, weight, outb, wsA, N);
        reduce1_kernel<<<96, 192, 0, stream>>>(wsA, wsB, nblocks);
        reduce2_kernel<<<1, 192, 0, stream>>>(wsB, gamma, beta, wsC, N);
        bn_apply_bf16_kernel<<<2040, 256, 0, stream>>>(outb, out, wsC, (long long)N * LPG);
    } else if (ws_size >= 2*bf_bytes + red_bytes) {
        // proven R6 path
        unsigned short* bdat = (unsigned short*)d_ws;
        unsigned short* outb = (unsigned short*)((char*)d_ws + bf_bytes);
        float* wsA = (float*)((char*)d_ws + 2*bf_bytes);
        float* wsB = wsA + (size_t)nblocks * 192;
        float* wsC = wsB + 96 * 192;
        cvt_kernel<<<2048, 256, 0, stream>>>(data, (ushortx8*)bdat, (long long)N*CCH/8);
        octconv_bf16_kernel<<<nblocks, TPB, 0, stream>>>(bdat, neigh, weight, outb, wsA, N);
        reduce1_kernel<<<96, 192, 0, stream>>>(wsA, wsB, nblocks);
        reduce2_kernel<<<1, 192, 0, stream>>>(wsB, gamma, beta, wsC, N);
        bn_apply_bf16_kernel<<<2040, 256, 0, stream>>>(outb, out, wsC, (long long)N * LPG);
    } else {
        float* wsA = (float*)d_ws;
        float* wsB = wsA + (size_t)nblocks * 192;
        float* wsC = wsB + 96 * 192;
        octconv_f32_kernel<<<nblocks, TPB, 0, stream>>>(data, neigh, weight, out, wsA, N);
        reduce1_kernel<<<96, 192, 0, stream>>>(wsA, wsB, nblocks);
        reduce2_kernel<<<1, 192, 0, stream>>>(wsB, gamma, beta, wsC, N);
        bn_apply_kernel<<<2040, 256, 0, stream>>>(out, wsC, (long long)N * C4);
    }
}

// Round 10
// 492.847 us; speedup vs baseline: 1.5067x; 1.0599x over previous
//
#include <hip/hip_runtime.h>

#define CCH 96      // channels
#define C4  24
#define KK  27      // neighbors
#define NPB 64      // nodes per conv block
#define TPB 192     // threads per conv block
#define BN_EPS 1e-5f
#define QROW 128    // padded int8 row bytes: 96 int8 + 4B scale + pad (2 aligned lines)

// conv geometry: 12 lanes x 8ch per node-row, 16 groups/block
#define LPG 12
#define GROUPS16 (TPB/LPG)        // 16
#define NPT16 (NPB/GROUPS16)      // 4
// fp32 fallback geometry
#define GROUPS8 8
#define NPT8 (NPB/GROUPS8)

typedef float floatx4 __attribute__((ext_vector_type(4)));
typedef unsigned short ushortx8 __attribute__((ext_vector_type(8)));
typedef signed char scharx8 __attribute__((ext_vector_type(8)));

__device__ __forceinline__ unsigned short f2bf_rne(float x){
    unsigned int u = __builtin_bit_cast(unsigned int, x);
    u += 0x7fffu + ((u >> 16) & 1u);
    return (unsigned short)(u >> 16);
}
__device__ __forceinline__ float bf2f(unsigned short h){
    unsigned int u = ((unsigned int)h) << 16;
    return __builtin_bit_cast(float, u);
}

// ---------------- fp32 -> int8(per-row scale) quantize ----------------
__global__ __launch_bounds__(256) void quant_kernel(
    const float* __restrict__ in, unsigned char* __restrict__ outq, int N)
{
    __shared__ float buf[64*CCH];          // 24576 B
    __shared__ float pmax[64][4];
    __shared__ float pscl[64], pinv[64];
    __shared__ __align__(16) unsigned char qbuf[64*QROW];  // 8192 B

    const int tid = threadIdx.x;
    const long long base = (long long)blockIdx.x * 64;

    floatx4* buf4 = (floatx4*)buf;
    const floatx4* in4 = (const floatx4*)in;
    for (int i = tid; i < 64*C4; i += 256) {
        const long long row = base + i / C4;
        buf4[i] = (row < N) ? in4[base*C4 + i] : (floatx4)0.f;
    }
    __syncthreads();

    const int r = tid >> 2;          // 0..63
    const int j = tid & 3;           // 0..3
    float m = 0.f;
    for (int c = j*24; c < j*24 + 24; ++c) m = fmaxf(m, fabsf(buf[r*CCH + c]));
    pmax[r][j] = m;
    __syncthreads();
    if (j == 0) {
        float mm = fmaxf(fmaxf(pmax[r][0], pmax[r][1]), fmaxf(pmax[r][2], pmax[r][3]));
        pscl[r] = mm * (1.f/127.f);
        pinv[r] = (mm > 0.f) ? (127.f / mm) : 0.f;
    }
    __syncthreads();
    const float inv = pinv[r];
    for (int c = j*24; c < j*24 + 24; ++c) {
        float q = rintf(buf[r*CCH + c] * inv);
        qbuf[r*QROW + c] = (unsigned char)(signed char)(int)q;
    }
    if (j == 0) {
        *(float*)(qbuf + r*QROW + 96) = pscl[r];
        for (int b = 100; b < QROW; b += 4) *(int*)(qbuf + r*QROW + b) = 0;
    }
    __syncthreads();

    uint4* out16 = (uint4*)outq;
    const uint4* q16 = (const uint4*)qbuf;
    for (int i = tid; i < 512; i += 256) {
        const long long row = base + (i >> 3);
        if (row < N) out16[base*8 + i] = q16[i];
    }
}

// ---------------- int8 conv + per-block BN partials (bf16 out) ----------------
// Branchless gather loop: clamped row index, validity folded into scale.
__global__ __launch_bounds__(TPB) void octconv_q8_kernel(
    const unsigned char* __restrict__ qdat,
    const int*   __restrict__ neigh32,
    const float* __restrict__ weight,
    unsigned short* __restrict__ outb,
    float*       __restrict__ partial,   // [gridDim.x][192]: 96 sum | 96 sumsq
    int N)
{
    __shared__ float w_lds[KK*CCH];                  // 10368 B
    __shared__ __align__(16) char u_lds[NPB*KK*4];   // 6912 B (nb, then red 6144 B)
    __shared__ int   flag_is64;
    int*   nb_lds = (int*)u_lds;
    float* red    = (float*)u_lds;

    const int tid  = threadIdx.x;
    const int l12  = tid % LPG;
    const int g    = tid / LPG;
    const int base = blockIdx.x * NPB;
    const long long totalK = (long long)N * KK;

    if (tid < 64) {
        int hi = neigh32[2*tid + 1];
        unsigned long long b = __ballot(hi != 0);
        if (tid == 0) flag_is64 = (b == 0ull) ? 1 : 0;
    }
    for (int i = tid; i < KK*CCH; i += TPB) w_lds[i] = weight[i];
    __syncthreads();

    const bool is64 = (flag_is64 != 0);
    const long long* neigh64 = (const long long*)neigh32;

    for (int i = tid; i < NPB*KK; i += TPB) {
        long long gi = (long long)base * KK + i;
        int v = -1;
        if (gi < totalK) {
            if (is64) { long long vv = __builtin_nontemporal_load(neigh64 + gi); v = (vv < 0) ? -1 : (int)vv; }
            else      { v = __builtin_nontemporal_load(neigh32 + gi); }
        }
        nb_lds[i] = v;
    }
    __syncthreads();

    floatx4 sA = (floatx4)0.f, sB = (floatx4)0.f;
    floatx4 qA = (floatx4)0.f, qB = (floatx4)0.f;
    const int ch0 = l12 * 8;

    for (int i = 0; i < NPT16; ++i) {
        const int local = g * NPT16 + i;
        const int n = base + local;
        if (n < N) {
            floatx4 accA = (floatx4)0.f, accB = (floatx4)0.f;
            #pragma unroll
            for (int k = 0; k < KK; ++k) {
                const int idx = nb_lds[local*KK + k];
                // unconditional load from clamped row; invalid -> scale 0
                const unsigned char* rp = qdat + ((long long)(idx < 0 ? 0 : idx) << 7);
                const scharx8 dq = *(const scharx8*)(rp + ch0);
                float s = *(const float*)(rp + 96);
                s = (idx >= 0) ? s : 0.f;
                const floatx4 wA = *(const floatx4*)(&w_lds[k*CCH + ch0]);
                const floatx4 wB = *(const floatx4*)(&w_lds[k*CCH + ch0 + 4]);
                floatx4 fA, fB;
                fA.x=(float)dq[0]; fA.y=(float)dq[1]; fA.z=(float)dq[2]; fA.w=(float)dq[3];
                fB.x=(float)dq[4]; fB.y=(float)dq[5]; fB.z=(float)dq[6]; fB.w=(float)dq[7];
                accA += fA * (wA * s);
                accB += fB * (wB * s);
            }
            ushortx8 o;
            o[0]=f2bf_rne(accA.x); o[1]=f2bf_rne(accA.y); o[2]=f2bf_rne(accA.z); o[3]=f2bf_rne(accA.w);
            o[4]=f2bf_rne(accB.x); o[5]=f2bf_rne(accB.y); o[6]=f2bf_rne(accB.z); o[7]=f2bf_rne(accB.w);
            __builtin_nontemporal_store(o, (ushortx8*)(outb + (long long)n*CCH + ch0));
            sA += accA; sB += accB;
            qA += accA*accA; qB += accB*accB;
        }
    }

    __syncthreads();
    *(floatx4*)(&red[g*CCH + ch0])     = sA;
    *(floatx4*)(&red[g*CCH + ch0 + 4]) = sB;
    __syncthreads();
    if (tid < CCH) {
        float t = 0.f;
        #pragma unroll
        for (int gg = 0; gg < GROUPS16; ++gg) t += red[gg*CCH + tid];
        partial[blockIdx.x*2*CCH + tid] = t;
    }
    __syncthreads();
    *(floatx4*)(&red[g*CCH + ch0])     = qA;
    *(floatx4*)(&red[g*CCH + ch0 + 4]) = qB;
    __syncthreads();
    if (tid < CCH) {
        float t = 0.f;
        #pragma unroll
        for (int gg = 0; gg < GROUPS16; ++gg) t += red[gg*CCH + tid];
        partial[blockIdx.x*2*CCH + CCH + tid] = t;
    }
}

// ---------------- bf16 fallback: fp32->bf16 copy ----------------
__global__ __launch_bounds__(256) void cvt_kernel(
    const float* __restrict__ in, ushortx8* __restrict__ outp, long long total8)
{
    long long i = (long long)blockIdx.x * 256 + threadIdx.x;
    const long long stride = (long long)gridDim.x * 256;
    const floatx4* in4 = (const floatx4*)in;
    for (; i < total8; i += stride) {
        floatx4 a = in4[2*i], b = in4[2*i+1];
        ushortx8 o;
        o[0]=f2bf_rne(a.x); o[1]=f2bf_rne(a.y); o[2]=f2bf_rne(a.z); o[3]=f2bf_rne(a.w);
        o[4]=f2bf_rne(b.x); o[5]=f2bf_rne(b.y); o[6]=f2bf_rne(b.z); o[7]=f2bf_rne(b.w);
        outp[i] = o;
    }
}

// ---------------- bf16 fallback conv (R6 path, bf16 out) ----------------
__global__ __launch_bounds__(TPB) void octconv_bf16_kernel(
    const unsigned short* __restrict__ bdat,
    const int*   __restrict__ neigh32,
    const float* __restrict__ weight,
    unsigned short* __restrict__ outb,
    float*       __restrict__ partial,
    int N)
{
    __shared__ float w_lds[KK*CCH];
    __shared__ __align__(16) char u_lds[NPB*KK*4];
    __shared__ int   flag_is64;
    int*   nb_lds = (int*)u_lds;
    float* red    = (float*)u_lds;

    const int tid  = threadIdx.x;
    const int l12  = tid % LPG;
    const int g    = tid / LPG;
    const int base = blockIdx.x * NPB;
    const long long totalK = (long long)N * KK;

    if (tid < 64) {
        int hi = neigh32[2*tid + 1];
        unsigned long long b = __ballot(hi != 0);
        if (tid == 0) flag_is64 = (b == 0ull) ? 1 : 0;
    }
    for (int i = tid; i < KK*CCH; i += TPB) w_lds[i] = weight[i];
    __syncthreads();

    const bool is64 = (flag_is64 != 0);
    const long long* neigh64 = (const long long*)neigh32;

    for (int i = tid; i < NPB*KK; i += TPB) {
        long long gi = (long long)base * KK + i;
        int v = -1;
        if (gi < totalK) {
            if (is64) { long long vv = __builtin_nontemporal_load(neigh64 + gi); v = (vv < 0) ? -1 : (int)vv; }
            else      { v = __builtin_nontemporal_load(neigh32 + gi); }
        }
        nb_lds[i] = v;
    }
    __syncthreads();

    floatx4 sA = (floatx4)0.f, sB = (floatx4)0.f;
    floatx4 qA = (floatx4)0.f, qB = (floatx4)0.f;
    const int ch0 = l12 * 8;

    for (int i = 0; i < NPT16; ++i) {
        const int local = g * NPT16 + i;
        const int n = base + local;
        if (n < N) {
            floatx4 accA = (floatx4)0.f, accB = (floatx4)0.f;
            #pragma unroll
            for (int k = 0; k < KK; ++k) {
                const int idx = nb_lds[local*KK + k];
                if (idx >= 0) {
                    const ushortx8 d = *(const ushortx8*)(bdat + (long long)idx*CCH + ch0);
                    const floatx4 wA = *(const floatx4*)(&w_lds[k*CCH + ch0]);
                    const floatx4 wB = *(const floatx4*)(&w_lds[k*CCH + ch0 + 4]);
                    floatx4 fA, fB;
                    fA.x=bf2f(d[0]); fA.y=bf2f(d[1]); fA.z=bf2f(d[2]); fA.w=bf2f(d[3]);
                    fB.x=bf2f(d[4]); fB.y=bf2f(d[5]); fB.z=bf2f(d[6]); fB.w=bf2f(d[7]);
                    accA += fA * wA;
                    accB += fB * wB;
                }
            }
            ushortx8 o;
            o[0]=f2bf_rne(accA.x); o[1]=f2bf_rne(accA.y); o[2]=f2bf_rne(accA.z); o[3]=f2bf_rne(accA.w);
            o[4]=f2bf_rne(accB.x); o[5]=f2bf_rne(accB.y); o[6]=f2bf_rne(accB.z); o[7]=f2bf_rne(accB.w);
            __builtin_nontemporal_store(o, (ushortx8*)(outb + (long long)n*CCH + ch0));
            sA += accA; sB += accB;
            qA += accA*accA; qB += accB*accB;
        }
    }

    __syncthreads();
    *(floatx4*)(&red[g*CCH + ch0])     = sA;
    *(floatx4*)(&red[g*CCH + ch0 + 4]) = sB;
    __syncthreads();
    if (tid < CCH) {
        float t = 0.f;
        #pragma unroll
        for (int gg = 0; gg < GROUPS16; ++gg) t += red[gg*CCH + tid];
        partial[blockIdx.x*2*CCH + tid] = t;
    }
    __syncthreads();
    *(floatx4*)(&red[g*CCH + ch0])     = qA;
    *(floatx4*)(&red[g*CCH + ch0 + 4]) = qB;
    __syncthreads();
    if (tid < CCH) {
        float t = 0.f;
        #pragma unroll
        for (int gg = 0; gg < GROUPS16; ++gg) t += red[gg*CCH + tid];
        partial[blockIdx.x*2*CCH + CCH + tid] = t;
    }
}

// ---------------- fp32 full-fallback conv ----------------
__global__ __launch_bounds__(TPB) void octconv_f32_kernel(
    const float* __restrict__ data,
    const int*   __restrict__ neigh32,
    const float* __restrict__ weight,
    float*       __restrict__ out,
    float*       __restrict__ partial,
    int N)
{
    __shared__ float w_lds[KK*CCH];
    __shared__ __align__(16) char u_lds[NPB*KK*4];
    __shared__ int   flag_is64;
    int*   nb_lds = (int*)u_lds;
    float* red    = (float*)u_lds;

    const int tid = threadIdx.x;
    const int c4  = tid % C4;
    const int g   = tid / C4;
    const int base = blockIdx.x * NPB;
    const long long totalK = (long long)N * KK;

    if (tid < 64) {
        int hi = neigh32[2*tid + 1];
        unsigned long long b = __ballot(hi != 0);
        if (tid == 0) flag_is64 = (b == 0ull) ? 1 : 0;
    }
    for (int i = tid; i < KK*CCH; i += TPB) w_lds[i] = weight[i];
    __syncthreads();

    const bool is64 = (flag_is64 != 0);
    const long long* neigh64 = (const long long*)neigh32;

    for (int i = tid; i < NPB*KK; i += TPB) {
        long long gi = (long long)base * KK + i;
        int v = -1;
        if (gi < totalK) {
            if (is64) { long long vv = __builtin_nontemporal_load(neigh64 + gi); v = (vv < 0) ? -1 : (int)vv; }
            else      { v = __builtin_nontemporal_load(neigh32 + gi); }
        }
        nb_lds[i] = v;
    }
    __syncthreads();

    const floatx4* w4 = (const floatx4*)w_lds;
    floatx4 s = (floatx4)0.f, q = (floatx4)0.f;

    for (int i = 0; i < NPT8; ++i) {
        const int local = g * NPT8 + i;
        const int n = base + local;
        if (n < N) {
            floatx4 acc = (floatx4)0.f;
            #pragma unroll
            for (int k = 0; k < KK; ++k) {
                const int idx = nb_lds[local*KK + k];
                if (idx >= 0) {
                    const floatx4 d = *(const floatx4*)(data + (long long)idx*CCH + c4*4);
                    acc += d * w4[k*C4 + c4];
                }
            }
            __builtin_nontemporal_store(acc, (floatx4*)(out + (long long)n*CCH + c4*4));
            s += acc; q += acc*acc;
        }
    }

    __syncthreads();
    *(floatx4*)(&red[g*CCH + c4*4]) = s;
    __syncthreads();
    if (g == 0) {
        floatx4 ts = (floatx4)0.f;
        #pragma unroll
        for (int gg = 0; gg < GROUPS8; ++gg) ts += *(floatx4*)(&red[gg*CCH + c4*4]);
        *(floatx4*)(partial + blockIdx.x*2*CCH + c4*4) = ts;
    }
    __syncthreads();
    *(floatx4*)(&red[g*CCH + c4*4]) = q;
    __syncthreads();
    if (g == 0) {
        floatx4 tq = (floatx4)0.f;
        #pragma unroll
        for (int gg = 0; gg < GROUPS8; ++gg) tq += *(floatx4*)(&red[gg*CCH + c4*4]);
        *(floatx4*)(partial + blockIdx.x*2*CCH + CCH + c4*4) = tq;
    }
}

// ---------------- stage-1 reduce ----------------
__global__ __launch_bounds__(192) void reduce1_kernel(
    const float* __restrict__ partial, float* __restrict__ out2, int nblocks)
{
    const int col = threadIdx.x;
    float s = 0.f;
    for (int r = blockIdx.x; r < nblocks; r += gridDim.x)
        s += partial[r*192 + col];
    out2[blockIdx.x*192 + col] = s;
}

// ---------------- stage-2 reduce + scale/shift ----------------
__global__ __launch_bounds__(192) void reduce2_kernel(
    const float* __restrict__ in2, const float* __restrict__ gamma,
    const float* __restrict__ beta, float* __restrict__ scaleshift, int N)
{
    __shared__ float arr[192];
    const int col = threadIdx.x;
    float s = 0.f;
    for (int r = 0; r < 96; ++r) s += in2[r*192 + col];
    arr[col] = s;
    __syncthreads();
    if (col < CCH) {
        float invN = 1.f / (float)N;
        float mean = arr[col] * invN;
        float var  = arr[CCH + col] * invN - mean*mean;
        float sc   = gamma[col] * rsqrtf(var + BN_EPS);
        scaleshift[col]       = sc;
        scaleshift[CCH + col] = beta[col] - mean*sc;
    }
}

// ---------------- apply BN: bf16 in (ws) -> fp32 out ----------------
__global__ __launch_bounds__(256) void bn_apply_bf16_kernel(
    const unsigned short* __restrict__ outb,
    float* __restrict__ out,
    const float* __restrict__ scaleshift, long long total12)
{
    __shared__ float sc[CCH], sh[CCH];
    const int tid = threadIdx.x;
    if (tid < CCH) { sc[tid] = scaleshift[tid]; sh[tid] = scaleshift[CCH + tid]; }
    __syncthreads();
    const long long stride = (long long)gridDim.x * blockDim.x;
    long long i = (long long)blockIdx.x * blockDim.x + tid;
    const int ch0 = (int)(i % LPG) * 8;
    const floatx4 a0 = *(const floatx4*)(&sc[ch0]);
    const floatx4 a1 = *(const floatx4*)(&sc[ch0+4]);
    const floatx4 b0 = *(const floatx4*)(&sh[ch0]);
    const floatx4 b1 = *(const floatx4*)(&sh[ch0+4]);
    for (; i < total12; i += stride) {
        const long long n = i / LPG;
        const ushortx8 d = __builtin_nontemporal_load((const ushortx8*)(outb + n*CCH + ch0));
        floatx4 vA, vB;
        vA.x=bf2f(d[0]); vA.y=bf2f(d[1]); vA.z=bf2f(d[2]); vA.w=bf2f(d[3]);
        vB.x=bf2f(d[4]); vB.y=bf2f(d[5]); vB.z=bf2f(d[6]); vB.w=bf2f(d[7]);
        vA = vA*a0 + b0;
        vB = vB*a1 + b1;
        __builtin_nontemporal_store(vA, (floatx4*)(out + n*CCH + ch0));
        __builtin_nontemporal_store(vB, (floatx4*)(out + n*CCH + ch0 + 4));
    }
}

// ---------------- apply BN in place (fp32 fallback) ----------------
__global__ __launch_bounds__(256) void bn_apply_kernel(
    float* __restrict__ out, const float* __restrict__ scaleshift, long long total4)
{
    __shared__ float4 sc[C4], sh[C4];
    const int tid = threadIdx.x;
    if (tid < C4) {
        sc[tid] = ((const float4*)scaleshift)[tid];
        sh[tid] = ((const float4*)(scaleshift + CCH))[tid];
    }
    __syncthreads();
    const long long stride = (long long)gridDim.x * blockDim.x;
    long long i = (long long)blockIdx.x * blockDim.x + tid;
    const int c4 = (int)(i % C4);
    const float4 a = sc[c4], b = sh[c4];
    float4* o4 = (float4*)out;
    for (; i < total4; i += stride) {
        float4 v = o4[i];
        v.x = v.x*a.x + b.x; v.y = v.y*a.y + b.y;
        v.z = v.z*a.z + b.z; v.w = v.w*a.w + b.w;
        o4[i] = v;
    }
}

extern "C" void kernel_launch(void* const* d_in, const int* in_sizes, int n_in,
                              void* d_out, int out_size, void* d_ws, size_t ws_size,
                              hipStream_t stream) {
    const float* data   = (const float*)d_in[0];
    const int*   neigh  = (const int*)d_in[1];
    const float* weight = (const float*)d_in[2];
    const float* gamma  = (const float*)d_in[3];
    const float* beta   = (const float*)d_in[4];
    float* out = (float*)d_out;

    const int N = in_sizes[0] / CCH;
    const int nblocks = (N + NPB - 1) / NPB;

    const size_t q_bytes   = ((size_t)N * QROW + 255) & ~(size_t)255;
    const size_t bf_bytes  = ((size_t)N * CCH * 2 + 255) & ~(size_t)255;
    const size_t red_bytes = ((size_t)nblocks * 192 + 96*192 + 192) * 4;

    if (ws_size >= q_bytes + bf_bytes + red_bytes) {
        // int8 gather + bf16 out staging
        unsigned char* qdat  = (unsigned char*)d_ws;
        unsigned short* outb = (unsigned short*)((char*)d_ws + q_bytes);
        float* wsA = (float*)((char*)d_ws + q_bytes + bf_bytes);
        float* wsB = wsA + (size_t)nblocks * 192;
        float* wsC = wsB + 96 * 192;
        quant_kernel<<<(N + 63)/64, 256, 0, stream>>>(data, qdat, N);
        octconv_q8_kernel<<<nblocks, TPB, 0, stream>>>(qdat, neigh, weight, outb, wsA, N);
        reduce1_kernel<<<96, 192, 0, stream>>>(wsA, wsB, nblocks);
        reduce2_kernel<<<1, 192, 0, stream>>>(wsB, gamma, beta, wsC, N);
        bn_apply_bf16_kernel<<<2040, 256, 0, stream>>>(outb, out, wsC, (long long)N * LPG);
    } else if (ws_size >= 2*bf_bytes + red_bytes) {
        // proven R6 path
        unsigned short* bdat = (unsigned short*)d_ws;
        unsigned short* outb = (unsigned short*)((char*)d_ws + bf_bytes);
        float* wsA = (float*)((char*)d_ws + 2*bf_bytes);
        float* wsB = wsA + (size_t)nblocks * 192;
        float* wsC = wsB + 96 * 192;
        cvt_kernel<<<2048, 256, 0, stream>>>(data, (ushortx8*)bdat, (long long)N*CCH/8);
        octconv_bf16_kernel<<<nblocks, TPB, 0, stream>>>(bdat, neigh, weight, outb, wsA, N);
        reduce1_kernel<<<96, 192, 0, stream>>>(wsA, wsB, nblocks);
        reduce2_kernel<<<1, 192, 0, stream>>>(wsB, gamma, beta, wsC, N);
        bn_apply_bf16_kernel<<<2040, 256, 0, stream>>>(outb, out, wsC, (long long)N * LPG);
    } else {
        float* wsA = (float*)d_ws;
        float* wsB = wsA + (size_t)nblocks * 192;
        float* wsC = wsB + 96 * 192;
        octconv_f32_kernel<<<nblocks, TPB, 0, stream>>>(data, neigh, weight, out, wsA, N);
        reduce1_kernel<<<96, 192, 0, stream>>>(wsA, wsB, nblocks);
        reduce2_kernel<<<1, 192, 0, stream>>>(wsB, gamma, beta, wsC, N);
        bn_apply_kernel<<<2040, 256, 0, stream>>>(out, wsC, (long long)N * C4);
    }
}